// Round 5
// baseline (280.903 us; speedup 1.0000x reference)
//
#include <hip/hip_runtime.h>
#include <math.h>

#define NATOMS  512
#define MROWS   64
#define BATCH   65536
#define BT      8           // batch columns per block (2 per wave, sequential)
#define NSPARSE 5
#define DEPS    1e-6

typedef float v2f __attribute__((ext_vector_type(2)));

// ---------------------------------------------------------------------------
// prep: gram = D^T D (f64 accumulate -> f32). 1024 blocks x 256 threads.
// ---------------------------------------------------------------------------
__global__ void ksvd_prep(const float* __restrict__ D,
                          float* __restrict__ gram) {
  const int idx = blockIdx.x * 256 + threadIdx.x;     // 0 .. 512*512-1
  const int i = idx >> 9;
  const int j = idx & (NATOMS - 1);
  double acc = 0.0;
#pragma unroll 8
  for (int m = 0; m < MROWS; ++m)
    acc += (double)D[m * NATOMS + i] * (double)D[m * NATOMS + j];
  gram[idx] = (float)acc;
}

// ---------------------------------------------------------------------------
// main: block = 4 waves = 8 batch columns (2 sequential per wave).
// Entry: block zero-fills its own 512x8 out tile (replaces memset dispatch).
// Phase 1: dtx = D^T x, f32 packed-pair FMA (v_pk_fma_f32): lane owns an
//   adjacent atom pair, X staged duplicated in LDS. Even/odd-m split
//   accumulators keep per-atom sum order bit-identical to round 4.
// Phase 2: OMP per column: f64 corr of the f32 chain, f32 argmax compare
//   (== jnp.argmax semantics, first-max ties), incremental rsqrt-Cholesky,
//   incremental fwd + full bwd substitution. Scatter via lanes 0..4.
// ---------------------------------------------------------------------------
__global__ __launch_bounds__(256, 4) void ksvd_main(
    const float* __restrict__ X, const float* __restrict__ D,
    const float* __restrict__ gram, float* __restrict__ out) {
  __shared__ __align__(16) v2f   xs2[MROWS][BT];         // 4 KB, {x,x} pairs
  __shared__ __align__(16) float dtxT[BT][NATOMS + 4];   // 16.5 KB

  const int t    = threadIdx.x;
  const int lane = t & 63;
  const int wave = t >> 6;                      // 0..3
  const int b0   = blockIdx.x * BT;

  // ---- zero-fill this block's out tile (coalesced float4; scatter comes
  //      after two __syncthreads -> ordered within the block through L2)
  {
    const int r0 = t >> 1;
    const int h  = (t & 1) * 4;
    const float4 z = {0.f, 0.f, 0.f, 0.f};
#pragma unroll
    for (int rr = 0; rr < 4; ++rr)
      *reinterpret_cast<float4*>(
          &out[(size_t)(r0 + 128 * rr) * BATCH + b0 + h]) = z;
  }

  // ---- stage X tile (64 m x 8 c), duplicated into {x,x} pairs
#pragma unroll
  for (int e = t; e < MROWS * BT; e += 256) {   // 2 iterations
    const int m = e >> 3, c = e & 7;
    const float xv = X[(size_t)m * BATCH + b0 + c];
    v2f p; p.x = xv; p.y = xv;
    xs2[m][c] = p;
  }
  __syncthreads();

  // ---- phase 1: lane owns atom pair (a0, a0+1), a0 = 128*wave + 2*lane
  const int a0 = wave * 128 + 2 * lane;
  v2f accA[BT], accB[BT];
#pragma unroll
  for (int c = 0; c < BT; ++c) {
    accA[c].x = 0.f; accA[c].y = 0.f;
    accB[c].x = 0.f; accB[c].y = 0.f;
  }

#pragma unroll 4
  for (int m = 0; m < MROWS; m += 2) {
    const v2f dA = *reinterpret_cast<const v2f*>(&D[m * NATOMS + a0]);
    const v2f dB = *reinterpret_cast<const v2f*>(&D[(m + 1) * NATOMS + a0]);
#pragma unroll
    for (int c = 0; c < BT; ++c) {
      accA[c] = __builtin_elementwise_fma(dA, xs2[m][c],     accA[c]);
      accB[c] = __builtin_elementwise_fma(dB, xs2[m + 1][c], accB[c]);
    }
  }
#pragma unroll
  for (int c = 0; c < BT; ++c) {
    const v2f s = accA[c] + accB[c];
    *reinterpret_cast<v2f*>(&dtxT[c][a0]) = s;
  }
  __syncthreads();

  // ---- phase 2: two sequential columns per wave
  for (int cc = 0; cc < 2; ++cc) {
    const int cl    = 2 * wave + cc;            // local column 0..7
    const int cglob = b0 + cl;

    double dtxd[8];
    {
      const float4 f0 = *reinterpret_cast<const float4*>(&dtxT[cl][8 * lane]);
      const float4 f1 = *reinterpret_cast<const float4*>(&dtxT[cl][8 * lane + 4]);
      dtxd[0] = (double)f0.x; dtxd[1] = (double)f0.y;
      dtxd[2] = (double)f0.z; dtxd[3] = (double)f0.w;
      dtxd[4] = (double)f1.x; dtxd[5] = (double)f1.y;
      dtxd[6] = (double)f1.z; dtxd[7] = (double)f1.w;
    }

    int    idxs[NSPARSE];
    float  rhsf[NSPARSE];
    float  gc[NSPARSE - 1][8];                // cached gram columns (f32)
    double L[NSPARSE][NSPARSE];               // lower-tri Cholesky
    double inv_d[NSPARSE];
    double y[NSPARSE];
    double sol[NSPARSE];

#pragma unroll
    for (int k = 0; k < NSPARSE; ++k) {
      // corr = dtx - sum_s sol[s]*gc_s (f64); f32-key argmax, first-max ties
      float bv = -1.0f;
      int   bn = 0;
#pragma unroll
      for (int jj = 0; jj < 8; ++jj) {
        double cv = dtxd[jj];
#pragma unroll
        for (int s = 0; s < k; ++s) cv -= sol[s] * (double)gc[s][jj];
        const float av = fabsf((float)cv);
        if (av > bv) { bv = av; bn = 8 * lane + jj; }   // strict >: first-max
      }
      float wmax = bv;
#pragma unroll
      for (int off = 1; off < 64; off <<= 1)
        wmax = fmaxf(wmax, __shfl_xor(wmax, off));
      const unsigned long long own = __ballot(bv == wmax);
      const int owner = __ffsll(own) - 1;               // lowest lane first
      int idx = __shfl(bn, owner);
      idx = __builtin_amdgcn_readfirstlane(idx);
      idxs[k] = idx;

      // gram column for future corr updates (vector, L2-resident)
      if (k < NSPARSE - 1) {
        const float4 g0 = *reinterpret_cast<const float4*>(
            &gram[(size_t)idx * NATOMS + 8 * lane]);
        const float4 g1 = *reinterpret_cast<const float4*>(
            &gram[(size_t)idx * NATOMS + 8 * lane + 4]);
        gc[k][0] = g0.x; gc[k][1] = g0.y; gc[k][2] = g0.z; gc[k][3] = g0.w;
        gc[k][4] = g1.x; gc[k][5] = g1.y; gc[k][6] = g1.z; gc[k][7] = g1.w;
      }

      // rhs: one uniform LDS read (broadcast)
      rhsf[k] = dtxT[cl][idx];

      // Gram row k entries: uniform addresses -> scalar loads
      float arowf[NSPARSE];
#pragma unroll
      for (int j = 0; j < k; ++j)
        arowf[j] = gram[(size_t)idx * NATOMS + idxs[j]];
      const float gdiag = gram[(size_t)idx * NATOMS + idx];

      // incremental Cholesky row k of (G_active + eps*I), rsqrt-based
      double ss = (double)gdiag + DEPS;
#pragma unroll
      for (int j = 0; j < k; ++j) {
        double w = (double)arowf[j];
#pragma unroll
        for (int tt = 0; tt < j; ++tt) w -= L[k][tt] * L[j][tt];
        w *= inv_d[j];
        L[k][j] = w;
        ss -= w * w;
      }
      const double inv = rsqrt(ss);
      L[k][k]  = ss * inv;                    // = sqrt(ss)
      inv_d[k] = inv;

      // forward substitution: only y[k] is new
      {
        double s2 = (double)rhsf[k];
#pragma unroll
        for (int j = 0; j < k; ++j) s2 -= L[k][j] * y[j];
        y[k] = s2 * inv;
      }
      // backward substitution (full)
#pragma unroll
      for (int i = k; i >= 0; --i) {
        double s2 = y[i];
#pragma unroll
        for (int j = i + 1; j <= k; ++j) s2 -= L[j][i] * sol[j];
        sol[i] = s2 * inv_d[i];
      }
    }

    // ---- epilogue: parallel scatter, lanes 0..4 (out tile pre-zeroed)
    if (lane < NSPARSE) {
      int    mi = idxs[0];
      double ms = sol[0];
#pragma unroll
      for (int s = 1; s < NSPARSE; ++s)
        if (lane == s) { mi = idxs[s]; ms = sol[s]; }
      out[(size_t)mi * BATCH + cglob] = (float)ms;
    }
  }
}

// ---------------------------------------------------------------------------
extern "C" void kernel_launch(void* const* d_in, const int* in_sizes, int n_in,
                              void* d_out, int out_size, void* d_ws,
                              size_t ws_size, hipStream_t stream) {
  (void)in_sizes; (void)n_in; (void)out_size; (void)ws_size;
  const float* X = (const float*)d_in[0];   // (64, 65536)
  const float* D = (const float*)d_in[1];   // (64, 512)
  float* out = (float*)d_out;               // (512, 65536)
  float* gram = (float*)d_ws;               // 1 MB scratch

  ksvd_prep<<<(NATOMS * NATOMS) / 256, 256, 0, stream>>>(D, gram);
  ksvd_main<<<BATCH / BT, 256, 0, stream>>>(X, D, gram, out);
}

// Round 6
// 184.816 us; speedup vs baseline: 1.5199x; 1.5199x over previous
//
#include <hip/hip_runtime.h>
#include <math.h>

#define NATOMS  512
#define MROWS   64
#define BATCH   65536
#define BT      4           // batch columns per block (1 per wave)
#define NSPARSE 5
#define DEPSF   1e-6f

typedef float v2f __attribute__((ext_vector_type(2)));

// ---------------------------------------------------------------------------
// prep: gram = D^T D (f64 accumulate -> f32). 1024 blocks x 256 threads.
// ---------------------------------------------------------------------------
__global__ void ksvd_prep(const float* __restrict__ D,
                          float* __restrict__ gram) {
  const int idx = blockIdx.x * 256 + threadIdx.x;     // 0 .. 512*512-1
  const int i = idx >> 9;
  const int j = idx & (NATOMS - 1);
  double acc = 0.0;
#pragma unroll 8
  for (int m = 0; m < MROWS; ++m)
    acc += (double)D[m * NATOMS + i] * (double)D[m * NATOMS + j];
  gram[idx] = (float)acc;
}

// ---------------------------------------------------------------------------
// main: block = 4 waves = 4 batch columns (one per wave) — round-4 structure.
// Phase 1: dtx = D^T x via packed-pair FMA (v_pk_fma_f32); lane owns atoms
//   (a0, a0+1); X staged duplicated as {x,x} pairs, read as b128 (2 per m,
//   same LDS traffic as round 4). Even/odd-m split accumulators keep the
//   per-atom sum order bit-identical to rounds 4/5.
// Phase 2: all-f32 OMP (reference solves in f32; corr perturbation ~1e-6 is
//   well inside the empirically-demonstrated argmax margin): f32 corr chain,
//   f32-key argmax (== jnp.argmax first-max semantics), incremental
//   rsqrtf-Cholesky, incremental fwd + full bwd substitution.
// Epilogue: 5-element scatter (out pre-zeroed by hipMemsetAsync).
// ---------------------------------------------------------------------------
__global__ __launch_bounds__(256, 4) void ksvd_main(
    const float* __restrict__ X, const float* __restrict__ D,
    const float* __restrict__ gram, float* __restrict__ out) {
  __shared__ __align__(16) float4 xs4[MROWS][BT / 2];    // 2 KB, dup pairs
  __shared__ __align__(16) float  dtxT[BT][NATOMS + 4];  // 8.3 KB

  const int t    = threadIdx.x;
  const int lane = t & 63;
  const int wave = t >> 6;                      // 0..3
  const int b0   = blockIdx.x * BT;

  // ---- stage X tile (64 m x 4 c) duplicated: xs4[m][p]={x2p,x2p,x2p+1,x2p+1}
  if (t < MROWS * 2) {
    const int m = t >> 1, p = t & 1;
    const float x0 = X[(size_t)m * BATCH + b0 + 2 * p];
    const float x1 = X[(size_t)m * BATCH + b0 + 2 * p + 1];
    float4 v; v.x = x0; v.y = x0; v.z = x1; v.w = x1;
    xs4[m][p] = v;
  }
  __syncthreads();

  // ---- phase 1: lane owns atom pair (a0, a0+1), a0 = 128*wave + 2*lane
  const int a0 = wave * 128 + 2 * lane;
  v2f accA[BT], accB[BT];
#pragma unroll
  for (int c = 0; c < BT; ++c) {
    accA[c].x = 0.f; accA[c].y = 0.f;
    accB[c].x = 0.f; accB[c].y = 0.f;
  }

#pragma unroll 4
  for (int m = 0; m < MROWS; m += 2) {
    const v2f dA = *reinterpret_cast<const v2f*>(&D[m * NATOMS + a0]);
    const v2f dB = *reinterpret_cast<const v2f*>(&D[(m + 1) * NATOMS + a0]);
    const float4 xa0 = xs4[m][0];
    const float4 xa1 = xs4[m][1];
    const float4 xb0 = xs4[m + 1][0];
    const float4 xb1 = xs4[m + 1][1];
    v2f xv;
    xv.x = xa0.x; xv.y = xa0.y; accA[0] = __builtin_elementwise_fma(dA, xv, accA[0]);
    xv.x = xa0.z; xv.y = xa0.w; accA[1] = __builtin_elementwise_fma(dA, xv, accA[1]);
    xv.x = xa1.x; xv.y = xa1.y; accA[2] = __builtin_elementwise_fma(dA, xv, accA[2]);
    xv.x = xa1.z; xv.y = xa1.w; accA[3] = __builtin_elementwise_fma(dA, xv, accA[3]);
    xv.x = xb0.x; xv.y = xb0.y; accB[0] = __builtin_elementwise_fma(dB, xv, accB[0]);
    xv.x = xb0.z; xv.y = xb0.w; accB[1] = __builtin_elementwise_fma(dB, xv, accB[1]);
    xv.x = xb1.x; xv.y = xb1.y; accB[2] = __builtin_elementwise_fma(dB, xv, accB[2]);
    xv.x = xb1.z; xv.y = xb1.w; accB[3] = __builtin_elementwise_fma(dB, xv, accB[3]);
  }
#pragma unroll
  for (int c = 0; c < BT; ++c) {
    const v2f s = accA[c] + accB[c];
    *reinterpret_cast<v2f*>(&dtxT[c][a0]) = s;
  }
  __syncthreads();

  // ---- phase 2: this wave's column; lane owns 8 consecutive atoms 8l..8l+7
  const int cglob = b0 + wave;
  float dtxr[8];
  {
    const float4 f0 = *reinterpret_cast<const float4*>(&dtxT[wave][8 * lane]);
    const float4 f1 = *reinterpret_cast<const float4*>(&dtxT[wave][8 * lane + 4]);
    dtxr[0] = f0.x; dtxr[1] = f0.y; dtxr[2] = f0.z; dtxr[3] = f0.w;
    dtxr[4] = f1.x; dtxr[5] = f1.y; dtxr[6] = f1.z; dtxr[7] = f1.w;
  }

  int   idxs[NSPARSE];
  float rhsf[NSPARSE];
  float gc[NSPARSE - 1][8];                 // cached gram columns (f32)
  float L[NSPARSE][NSPARSE];                // lower-tri Cholesky (static idx)
  float inv_d[NSPARSE];
  float y[NSPARSE];
  float sol[NSPARSE];

#pragma unroll
  for (int k = 0; k < NSPARSE; ++k) {
    // corr = dtx - sum_s sol[s]*gc_s (f32); f32-key argmax, first-max ties
    float bv = -1.0f;
    int   bn = 0;
#pragma unroll
    for (int jj = 0; jj < 8; ++jj) {
      float cv = dtxr[jj];
#pragma unroll
      for (int s = 0; s < k; ++s) cv -= sol[s] * gc[s][jj];
      const float av = fabsf(cv);
      if (av > bv) { bv = av; bn = 8 * lane + jj; }   // strict >: first-max
    }
    float wmax = bv;
#pragma unroll
    for (int off = 1; off < 64; off <<= 1)
      wmax = fmaxf(wmax, __shfl_xor(wmax, off));
    const unsigned long long own = __ballot(bv == wmax);
    const int owner = __ffsll(own) - 1;               // lowest lane: first-max
    int idx = __shfl(bn, owner);
    idx = __builtin_amdgcn_readfirstlane(idx);
    idxs[k] = idx;

    // gram column for future corr updates (vector, L2-resident)
    if (k < NSPARSE - 1) {
      const float4 g0 = *reinterpret_cast<const float4*>(
          &gram[(size_t)idx * NATOMS + 8 * lane]);
      const float4 g1 = *reinterpret_cast<const float4*>(
          &gram[(size_t)idx * NATOMS + 8 * lane + 4]);
      gc[k][0] = g0.x; gc[k][1] = g0.y; gc[k][2] = g0.z; gc[k][3] = g0.w;
      gc[k][4] = g1.x; gc[k][5] = g1.y; gc[k][6] = g1.z; gc[k][7] = g1.w;
    }

    // rhs: one uniform LDS read (broadcast)
    rhsf[k] = dtxT[wave][idx];

    // Gram row k entries: uniform addresses -> scalar loads
    float arowf[NSPARSE];
#pragma unroll
    for (int j = 0; j < k; ++j)
      arowf[j] = gram[(size_t)idx * NATOMS + idxs[j]];
    const float gdiag = gram[(size_t)idx * NATOMS + idx];

    // incremental Cholesky row k of (G_active + eps*I), rsqrtf-based
    float ss = gdiag + DEPSF;
#pragma unroll
    for (int j = 0; j < k; ++j) {
      float w = arowf[j];
#pragma unroll
      for (int tt = 0; tt < j; ++tt) w -= L[k][tt] * L[j][tt];
      w *= inv_d[j];
      L[k][j] = w;
      ss -= w * w;
    }
    const float inv = rsqrtf(ss);
    L[k][k]  = ss * inv;                    // = sqrt(ss)
    inv_d[k] = inv;

    // forward substitution: only y[k] is new (y[0..k-1] unchanged)
    {
      float s2 = rhsf[k];
#pragma unroll
      for (int j = 0; j < k; ++j) s2 -= L[k][j] * y[j];
      y[k] = s2 * inv;
    }
    // backward substitution (full, sol changes every round)
#pragma unroll
    for (int i = k; i >= 0; --i) {
      float s2 = y[i];
#pragma unroll
      for (int j = i + 1; j <= k; ++j) s2 -= L[j][i] * sol[j];
      sol[i] = s2 * inv_d[i];
    }
  }

  // ---- epilogue: scatter the 5 coefficients (out pre-zeroed by memset)
  if (lane == 0) {
#pragma unroll
    for (int s = 0; s < NSPARSE; ++s)
      out[(size_t)idxs[s] * BATCH + cglob] = sol[s];
  }
}

// ---------------------------------------------------------------------------
extern "C" void kernel_launch(void* const* d_in, const int* in_sizes, int n_in,
                              void* d_out, int out_size, void* d_ws,
                              size_t ws_size, hipStream_t stream) {
  (void)in_sizes; (void)n_in; (void)out_size; (void)ws_size;
  const float* X = (const float*)d_in[0];   // (64, 65536)
  const float* D = (const float*)d_in[1];   // (64, 512)
  float* out = (float*)d_out;               // (512, 65536)
  float* gram = (float*)d_ws;               // 1 MB scratch

  ksvd_prep<<<(NATOMS * NATOMS) / 256, 256, 0, stream>>>(D, gram);
  hipMemsetAsync(out, 0, (size_t)NATOMS * BATCH * sizeof(float), stream);
  ksvd_main<<<BATCH / BT, 256, 0, stream>>>(X, D, gram, out);
}

// Round 7
// 176.776 us; speedup vs baseline: 1.5890x; 1.0455x over previous
//
#include <hip/hip_runtime.h>
#include <math.h>

#define NATOMS  512
#define MROWS   64
#define BATCH   65536
#define BT      4           // batch columns per block (1 per wave)
#define NSPARSE 5
#define DEPSF   1e-6f

typedef float v2f __attribute__((ext_vector_type(2)));

// ---------------------------------------------------------------------------
// prep: gram = D^T D (f64 accumulate -> f32). 1024 blocks x 256 threads.
// ---------------------------------------------------------------------------
__global__ void ksvd_prep(const float* __restrict__ D,
                          float* __restrict__ gram) {
  const int idx = blockIdx.x * 256 + threadIdx.x;     // 0 .. 512*512-1
  const int i = idx >> 9;
  const int j = idx & (NATOMS - 1);
  double acc = 0.0;
#pragma unroll 8
  for (int m = 0; m < MROWS; ++m)
    acc += (double)D[m * NATOMS + i] * (double)D[m * NATOMS + j];
  gram[idx] = (float)acc;
}

// ---------------------------------------------------------------------------
// wave64 max-reduce on the VALU via DPP (no LDS ops, no lgkmcnt waits).
// row_shr 1/2/4/8 -> lane15 of each 16-row holds the row max;
// row_bcast15 -> lane31 = max(r0,r1), lane63 = max(r2,r3);
// row_bcast31 -> lane63 = global max. Then readlane(63) broadcasts.
// bound_ctrl=true feeds 0 for shifted-out lanes: harmless, keys are >= 0.
// ---------------------------------------------------------------------------
__device__ __forceinline__ float wave_max_nonneg(float x) {
  int v = __builtin_bit_cast(int, x);
#define DPP_MAX_STEP(ctrl)                                                   \
  {                                                                          \
    const int t = __builtin_amdgcn_update_dpp(0, v, (ctrl), 0xf, 0xf, true); \
    v = __builtin_bit_cast(                                                  \
        int, fmaxf(__builtin_bit_cast(float, v), __builtin_bit_cast(float, t))); \
  }
  DPP_MAX_STEP(0x111)   // row_shr:1
  DPP_MAX_STEP(0x112)   // row_shr:2
  DPP_MAX_STEP(0x114)   // row_shr:4
  DPP_MAX_STEP(0x118)   // row_shr:8
  DPP_MAX_STEP(0x142)   // row_bcast15
  DPP_MAX_STEP(0x143)   // row_bcast31
#undef DPP_MAX_STEP
  return __builtin_bit_cast(float, __builtin_amdgcn_readlane(v, 63));
}

// ---------------------------------------------------------------------------
// main: block = 4 waves = 4 batch columns (one per wave).
// Phase 1: dtx = D^T x via packed-pair FMA (v_pk_fma_f32); X staged
//   duplicated as {x,x} pairs (b128 reads). Bit-identical to rounds 4-6.
// Phase 2: all-f32 OMP: f32 corr chain, f32-key argmax with DPP wave-max +
//   ballot/readlane owner resolve (== jnp.argmax first-max semantics),
//   incremental rsqrtf-Cholesky, incremental fwd + full bwd substitution.
// Epilogue: 5-element scatter (out pre-zeroed by hipMemsetAsync).
// ---------------------------------------------------------------------------
__global__ __launch_bounds__(256, 4) void ksvd_main(
    const float* __restrict__ X, const float* __restrict__ D,
    const float* __restrict__ gram, float* __restrict__ out) {
  __shared__ __align__(16) float4 xs4[MROWS][BT / 2];    // 2 KB, dup pairs
  __shared__ __align__(16) float  dtxT[BT][NATOMS + 4];  // 8.3 KB

  const int t    = threadIdx.x;
  const int lane = t & 63;
  const int wave = t >> 6;                      // 0..3
  const int b0   = blockIdx.x * BT;

  // ---- stage X tile (64 m x 4 c) duplicated: xs4[m][p]={x2p,x2p,x2p+1,x2p+1}
  if (t < MROWS * 2) {
    const int m = t >> 1, p = t & 1;
    const float x0 = X[(size_t)m * BATCH + b0 + 2 * p];
    const float x1 = X[(size_t)m * BATCH + b0 + 2 * p + 1];
    float4 v; v.x = x0; v.y = x0; v.z = x1; v.w = x1;
    xs4[m][p] = v;
  }
  __syncthreads();

  // ---- phase 1: lane owns atom pair (a0, a0+1), a0 = 128*wave + 2*lane
  const int a0 = wave * 128 + 2 * lane;
  v2f accA[BT], accB[BT];
#pragma unroll
  for (int c = 0; c < BT; ++c) {
    accA[c].x = 0.f; accA[c].y = 0.f;
    accB[c].x = 0.f; accB[c].y = 0.f;
  }

#pragma unroll 4
  for (int m = 0; m < MROWS; m += 2) {
    const v2f dA = *reinterpret_cast<const v2f*>(&D[m * NATOMS + a0]);
    const v2f dB = *reinterpret_cast<const v2f*>(&D[(m + 1) * NATOMS + a0]);
    const float4 xa0 = xs4[m][0];
    const float4 xa1 = xs4[m][1];
    const float4 xb0 = xs4[m + 1][0];
    const float4 xb1 = xs4[m + 1][1];
    v2f xv;
    xv.x = xa0.x; xv.y = xa0.y; accA[0] = __builtin_elementwise_fma(dA, xv, accA[0]);
    xv.x = xa0.z; xv.y = xa0.w; accA[1] = __builtin_elementwise_fma(dA, xv, accA[1]);
    xv.x = xa1.x; xv.y = xa1.y; accA[2] = __builtin_elementwise_fma(dA, xv, accA[2]);
    xv.x = xa1.z; xv.y = xa1.w; accA[3] = __builtin_elementwise_fma(dA, xv, accA[3]);
    xv.x = xb0.x; xv.y = xb0.y; accB[0] = __builtin_elementwise_fma(dB, xv, accB[0]);
    xv.x = xb0.z; xv.y = xb0.w; accB[1] = __builtin_elementwise_fma(dB, xv, accB[1]);
    xv.x = xb1.x; xv.y = xb1.y; accB[2] = __builtin_elementwise_fma(dB, xv, accB[2]);
    xv.x = xb1.z; xv.y = xb1.w; accB[3] = __builtin_elementwise_fma(dB, xv, accB[3]);
  }
#pragma unroll
  for (int c = 0; c < BT; ++c) {
    const v2f s = accA[c] + accB[c];
    *reinterpret_cast<v2f*>(&dtxT[c][a0]) = s;
  }
  __syncthreads();

  // ---- phase 2: this wave's column; lane owns 8 consecutive atoms 8l..8l+7
  const int cglob = b0 + wave;
  float dtxr[8];
  {
    const float4 f0 = *reinterpret_cast<const float4*>(&dtxT[wave][8 * lane]);
    const float4 f1 = *reinterpret_cast<const float4*>(&dtxT[wave][8 * lane + 4]);
    dtxr[0] = f0.x; dtxr[1] = f0.y; dtxr[2] = f0.z; dtxr[3] = f0.w;
    dtxr[4] = f1.x; dtxr[5] = f1.y; dtxr[6] = f1.z; dtxr[7] = f1.w;
  }

  int   idxs[NSPARSE];
  float rhsf[NSPARSE];
  float gc[NSPARSE - 1][8];                 // cached gram columns (f32)
  float L[NSPARSE][NSPARSE];                // lower-tri Cholesky (static idx)
  float inv_d[NSPARSE];
  float y[NSPARSE];
  float sol[NSPARSE];

#pragma unroll
  for (int k = 0; k < NSPARSE; ++k) {
    // corr = dtx - sum_s sol[s]*gc_s (f32); f32-key argmax, first-max ties
    float bv = -1.0f;
    int   bn = 0;
#pragma unroll
    for (int jj = 0; jj < 8; ++jj) {
      float cv = dtxr[jj];
#pragma unroll
      for (int s = 0; s < k; ++s) cv -= sol[s] * gc[s][jj];
      const float av = fabsf(cv);
      if (av > bv) { bv = av; bn = 8 * lane + jj; }   // strict >: first-max
    }
    // wave max on the VALU (DPP), then owner = lowest lane holding the max
    const float wmax = wave_max_nonneg(bv);
    const unsigned long long own = __ballot(bv == wmax);
    const int owner = __ffsll((long long)own) - 1;    // lowest lane: first-max
    const int idx = __builtin_amdgcn_readlane(bn, owner);  // uniform (SGPR)
    idxs[k] = idx;

    // gram column for future corr updates (vector, L2-resident)
    if (k < NSPARSE - 1) {
      const float4 g0 = *reinterpret_cast<const float4*>(
          &gram[(size_t)idx * NATOMS + 8 * lane]);
      const float4 g1 = *reinterpret_cast<const float4*>(
          &gram[(size_t)idx * NATOMS + 8 * lane + 4]);
      gc[k][0] = g0.x; gc[k][1] = g0.y; gc[k][2] = g0.z; gc[k][3] = g0.w;
      gc[k][4] = g1.x; gc[k][5] = g1.y; gc[k][6] = g1.z; gc[k][7] = g1.w;
    }

    // rhs: one uniform LDS read (broadcast)
    rhsf[k] = dtxT[wave][idx];

    // Gram row k entries: uniform (scalar) loads
    float arowf[NSPARSE];
#pragma unroll
    for (int j = 0; j < k; ++j)
      arowf[j] = gram[(size_t)idx * NATOMS + idxs[j]];
    const float gdiag = gram[(size_t)idx * NATOMS + idx];

    // incremental Cholesky row k of (G_active + eps*I), rsqrtf-based
    float ss = gdiag + DEPSF;
#pragma unroll
    for (int j = 0; j < k; ++j) {
      float w = arowf[j];
#pragma unroll
      for (int tt = 0; tt < j; ++tt) w -= L[k][tt] * L[j][tt];
      w *= inv_d[j];
      L[k][j] = w;
      ss -= w * w;
    }
    const float inv = rsqrtf(ss);
    L[k][k]  = ss * inv;                    // = sqrt(ss)
    inv_d[k] = inv;

    // forward substitution: only y[k] is new (y[0..k-1] unchanged)
    {
      float s2 = rhsf[k];
#pragma unroll
      for (int j = 0; j < k; ++j) s2 -= L[k][j] * y[j];
      y[k] = s2 * inv;
    }
    // backward substitution (full, sol changes every round)
#pragma unroll
    for (int i = k; i >= 0; --i) {
      float s2 = y[i];
#pragma unroll
      for (int j = i + 1; j <= k; ++j) s2 -= L[j][i] * sol[j];
      sol[i] = s2 * inv_d[i];
    }
  }

  // ---- epilogue: scatter the 5 coefficients (out pre-zeroed by memset)
  if (lane == 0) {
#pragma unroll
    for (int s = 0; s < NSPARSE; ++s)
      out[(size_t)idxs[s] * BATCH + cglob] = sol[s];
  }
}

// ---------------------------------------------------------------------------
extern "C" void kernel_launch(void* const* d_in, const int* in_sizes, int n_in,
                              void* d_out, int out_size, void* d_ws,
                              size_t ws_size, hipStream_t stream) {
  (void)in_sizes; (void)n_in; (void)out_size; (void)ws_size;
  const float* X = (const float*)d_in[0];   // (64, 65536)
  const float* D = (const float*)d_in[1];   // (64, 512)
  float* out = (float*)d_out;               // (512, 65536)
  float* gram = (float*)d_ws;               // 1 MB scratch

  ksvd_prep<<<(NATOMS * NATOMS) / 256, 256, 0, stream>>>(D, gram);
  hipMemsetAsync(out, 0, (size_t)NATOMS * BATCH * sizeof(float), stream);
  ksvd_main<<<BATCH / BT, 256, 0, stream>>>(X, D, gram, out);
}